// Round 5
// baseline (187.892 us; speedup 1.0000x reference)
//
#include <hip/hip_runtime.h>
#include <math.h>

// TQUnitaryBuilder: 9-wire, 4-layer circuit -> U (512x512 real) per sample,
// fused MLP-prep + circuit sim in ONE kernel, plus closed-form rank-2 expm
// correction kernel (cols 0..71).
//
// x bit convention: wire w lives at bit 8-w. Ring CNOT perm F (forward):
// y_k = XOR_{m>=k,m<=7} x_m (k<=7), y_8 = x_8 ^ y_0. LDS swizzle
// phys(x) = x ^ ((x>>4)&15); both GF(2)-linear; all LDS patterns audited
// conflict-free (4 lanes per pair-bank).
//
// Per layer: 9 real rotations (packed fp32) + ONE deferred diagonal phase
// D(x) = B[x>>6]*A[x&63] (phases of all wires commute with rotations).
//
// ws layout: per sample s, 80 floats at ws + s*80:
//   [0..71] v (0.01*params, v[0]=0); [72] cos(th); [73] alpha; [74] beta

__device__ __forceinline__ float2 cmul(float2 a, float2 b){
  return make_float2(fmaf(a.x, b.x, -a.y*b.y), fmaf(a.x, b.y, a.y*b.x));
}
// packed fp32: d = bcast(a.x or a.y) * b (+ c), element-wise on float2
__device__ __forceinline__ float2 pk_fma_lo(float2 a, float2 b, float2 c){
  float2 d;
  asm("v_pk_fma_f32 %0, %1, %2, %3 op_sel:[0,0,0] op_sel_hi:[0,1,1]"
      : "=v"(d) : "v"(a), "v"(b), "v"(c));
  return d;
}
__device__ __forceinline__ float2 pk_mul_hi(float2 a, float2 b){
  float2 d;
  asm("v_pk_mul_f32 %0, %1, %2 op_sel:[1,0] op_sel_hi:[1,1]"
      : "=v"(d) : "v"(a), "v"(b));
  return d;
}
__device__ __forceinline__ float2 pk_swapneg(float2 c, float2 n){
  float2 d;  // d = (-c.y, c.x) with n = (-1, 1)
  asm("v_pk_mul_f32 %0, %1, %2 op_sel:[1,0] op_sel_hi:[0,1]"
      : "=v"(d) : "v"(c), "v"(n));
  return d;
}

__device__ __forceinline__ int Fperm(int x){       // forward ring permutation
  int S = x ^ (x >> 1); S ^= S >> 2; S ^= S >> 4; S ^= S >> 8;
  return (S & 0xFF) | ((((x >> 8) ^ S) & 1) << 8);
}
__device__ __forceinline__ int physmap(int x){ return x ^ ((x >> 4) & 15); }

template<int STRIDE>
__device__ __forceinline__ void apply_rot(float2 amp[8], float4 rc){
  const float2 R0 = make_float2(rc.x, rc.y);   // (c, -s)
  const float2 R1 = make_float2(rc.z, rc.w);   // (s,  c)
  #pragma unroll
  for (int b = 0; b < 8; ++b){
    if (b & STRIDE) continue;
    const float2 u = amp[b], v = amp[b + STRIDE];
    amp[b]          = pk_fma_lo(R0, u, pk_mul_hi(R0, v));  // c*u - s*v
    amp[b + STRIDE] = pk_fma_lo(R1, u, pk_mul_hi(R1, v));  // s*u + c*v
  }
}

// LDS table offsets (floats) inside buf[]
#define LDS_L1G 0      // layer-1 full gates: 9 x 8
#define LDS_ROT 72     // rot coeffs layers 2..4: 27 x (c,-s,s,c)
#define LDS_BPH 180    // B phase: 3 layers x 8 x (Br,Bi,-Bi,Br)
#define LDS_APH 288    // A phase: 3 layers x 64 x (Ar,Ai)
#define BUF_FLOATS 1160

// ---------------- kernel 1: fused prep + circuit sim ----------------
// Grid: blockIdx = cb*64 + s (output 64B-line pairs on the same XCD).
// Block 512 thr = 8 waves, one wave per column, st[wid] wave-private ->
// no barriers in the layer loop.
__global__ __launch_bounds__(512, 6)
void sim_kernel(const float* __restrict__ t,  const float* __restrict__ w1,
                const float* __restrict__ b1, const float* __restrict__ w2,
                const float* __restrict__ b2,
                float* __restrict__ out, float* __restrict__ ws){
  __shared__ __align__(16) float2 st[8][512];
  __shared__ __align__(16) float buf[BUF_FLOATS];
  __shared__ float spar[72];
  const int s    = blockIdx.x & 63;
  const int cb   = blockIdx.x >> 6;
  const int tid  = threadIdx.x;
  const int wid  = tid >> 6;
  const int lane = tid & 63;
  const int col  = cb*8 + wid;               // input basis state / U column
  float2* const S = st[wid];
  const float2 NEG1P1 = make_float2(-1.f, 1.f);

  // ======== fused prep: MLP -> params -> gate/phase tables in LDS ========
  {
    const float ts = t[s];
    const float z = fmaf(ts, w1[tid], b1[tid]);
    buf[tid] = z / (1.f + expf(-z));         // silu, h[512]
  }
  __syncthreads();
  {
    const int c = tid >> 7, p = tid & 127;   // 4 chunks x 128 k
    if (p < 72){
      float acc = 0.f;
      const int k0 = c*128;
      #pragma unroll 4
      for (int k = k0; k < k0+128; ++k) acc = fmaf(buf[k], w2[k*72 + p], acc);
      buf[512 + c*72 + p] = acc;             // partials, disjoint from h
    }
  }
  __syncthreads();
  if (tid < 72)
    spar[tid] = b2[tid] + buf[512+tid] + buf[584+tid] + buf[656+tid] + buf[728+tid];
  __syncthreads();
  // tables (overwrite buf; spar is separate)
  if (tid < 27){                             // rot coeffs, layers 2..4
    const int l = tid/9, w = tid - l*9;
    const float thy = spar[2*(9*(l+1) + w)];
    float sy, cy; sincosf(0.5f*thy, &sy, &cy);
    float* o = buf + LDS_ROT + tid*4;
    o[0] = cy; o[1] = -sy; o[2] = sy; o[3] = cy;
  } else if (tid >= 32 && tid < 41){         // layer-1 full gates
    const int w = tid - 32;
    const float thy = spar[2*w], thz = spar[2*w + 1];
    float sy, cy, zi, zr;
    sincosf(0.5f*thy, &sy, &cy);
    sincosf(0.5f*thz, &zi, &zr);             // e = (zr, zi)
    float* o = buf + LDS_L1G + w*8;
    o[0] =  zr*cy; o[1] = -zi*cy;            // g00 = conj(e)*c
    o[2] = -zr*sy; o[3] =  zi*sy;            // g01 = -conj(e)*s
    o[4] =  zr*sy; o[5] =  zi*sy;            // g10 = e*s
    o[6] =  zr*cy; o[7] =  zi*cy;            // g11 = e*c
  } else if (tid >= 64 && tid < 88){         // B phase: signed angle sum
    const int q = tid - 64, l = q >> 3, j = q & 7;
    float ang = 0.f;
    #pragma unroll
    for (int w = 0; w < 3; ++w){
      const float thz = spar[2*(9*(l+1) + w) + 1];
      ang += ((j >> (2 - w)) & 1) ? thz : -thz;
    }
    float si, co; sincosf(0.5f*ang, &si, &co);
    float* o = buf + LDS_BPH + q*4;
    o[0] = co; o[1] = si; o[2] = -si; o[3] = co;
  } else if (tid >= 128 && tid < 320){       // A phase: signed angle sum
    const int q = tid - 128, l = q >> 6, m = q & 63;
    float ang = 0.f;
    #pragma unroll
    for (int w = 3; w < 9; ++w){
      const float thz = spar[2*(9*(l+1) + w) + 1];
      ang += ((m >> (8 - w)) & 1) ? thz : -thz;
    }
    float si, co; sincosf(0.5f*ang, &si, &co);
    float* o = buf + LDS_APH + q*2;
    o[0] = co; o[1] = si;
  } else if (cb == 0 && tid >= 320 && tid < 392){  // v for corr
    const int j = tid - 320;
    ws[s*80 + j] = (j == 0) ? 0.f : 0.01f*spar[j];
  } else if (cb == 0 && tid == 392){         // expm scalars for corr
    float th2 = 0.f;
    for (int j = 1; j < 72; ++j){ const float v = 0.01f*spar[j]; th2 = fmaf(v, v, th2); }
    const float th = sqrtf(th2);
    float alpha, beta;
    if (th > 1e-6f){
      alpha = sinf(th)/th;
      const float s2 = sinf(0.5f*th);
      beta = 2.f*s2*s2/th2;
    } else { alpha = 1.f - th2/6.f; beta = 0.5f; }
    ws[s*80 + 72] = cosf(th);
    ws[s*80 + 73] = alpha;
    ws[s*80 + 74] = beta;
  }
  __syncthreads();

  // ======== circuit simulation ========
  float2 amp[8];
  // ---- layer 1 on basis state |col> : product state, O(D) ----
  {
    float2 base = make_float2(1.f, 0.f);
    #pragma unroll
    for (int w = 0; w < 6; ++w){
      const int xb = (lane >> (5 - w)) & 1;  // x bit 8-w  (lane = x>>3)
      const int ib = (col  >> (8 - w)) & 1;  // input bit of wire w
      const float2 ge = *(const float2*)&buf[LDS_L1G + 8*w + (xb*2 + ib)*2];
      base = cmul(base, ge);
    }
    const int i6 = (col >> 2) & 1, i7 = (col >> 1) & 1, i8 = col & 1;
    float2 G6[2], G7[2], G8[2];
    #pragma unroll
    for (int r = 0; r < 2; ++r){
      G6[r] = *(const float2*)&buf[LDS_L1G + 48 + (r*2 + i6)*2];
      G7[r] = *(const float2*)&buf[LDS_L1G + 56 + (r*2 + i7)*2];
      G8[r] = *(const float2*)&buf[LDS_L1G + 64 + (r*2 + i8)*2];
    }
    #pragma unroll
    for (int j = 0; j < 8; ++j){
      const float2 tj = cmul(cmul(G6[(j>>2)&1], G7[(j>>1)&1]), G8[j&1]);
      amp[j] = cmul(base, tj);
    }
    // write with ring-1 folded: element x = 8*lane + j -> slot phys(F(x))
    const int bFI = physmap(Fperm(lane << 3));
    #pragma unroll
    for (int j = 0; j < 8; ++j) S[bFI ^ physmap(Fperm(j))] = amp[j];
  }

  const int base1 = (lane << 3) ^ ((lane >> 1) & 15);            // phys(8*lane)
  const int hq = lane >> 3, lq = lane & 7;
  const int base2 = (hq << 6) ^ ((hq << 2) & 15) ^ lq;           // phys(64h)^l
  const int base3 = lane ^ (lane >> 4);                          // phys(lane)
  const int baseF = physmap(Fperm(lane));

  #pragma unroll
  for (int L = 0; L < 3; ++L){
    // round 1: wires 6,7,8 (x bits 2..0) — linear read (ring already folded)
    #pragma unroll
    for (int j = 0; j < 8; ++j) amp[j] = S[base1 ^ j];
    apply_rot<4>(amp, *(const float4*)&buf[LDS_ROT + (L*9 + 6)*4]);
    apply_rot<2>(amp, *(const float4*)&buf[LDS_ROT + (L*9 + 7)*4]);
    apply_rot<1>(amp, *(const float4*)&buf[LDS_ROT + (L*9 + 8)*4]);
    #pragma unroll
    for (int j = 0; j < 8; ++j) S[base1 ^ j] = amp[j];
    // round 2: wires 3,4,5 (x bits 5..3); x = 64h + 8j + l
    #pragma unroll
    for (int j = 0; j < 8; ++j) amp[j] = S[base2 ^ ((j << 3) ^ (j >> 1))];
    apply_rot<4>(amp, *(const float4*)&buf[LDS_ROT + (L*9 + 3)*4]);
    apply_rot<2>(amp, *(const float4*)&buf[LDS_ROT + (L*9 + 4)*4]);
    apply_rot<1>(amp, *(const float4*)&buf[LDS_ROT + (L*9 + 5)*4]);
    #pragma unroll
    for (int j = 0; j < 8; ++j) S[base2 ^ ((j << 3) ^ (j >> 1))] = amp[j];
    // round 3: wires 0,1,2 (x bits 8..6); x = 64j + lane
    #pragma unroll
    for (int j = 0; j < 8; ++j) amp[j] = S[base3 ^ ((j << 6) ^ ((4*j) & 15))];
    apply_rot<4>(amp, *(const float4*)&buf[LDS_ROT + (L*9 + 0)*4]);
    apply_rot<2>(amp, *(const float4*)&buf[LDS_ROT + (L*9 + 1)*4]);
    apply_rot<1>(amp, *(const float4*)&buf[LDS_ROT + (L*9 + 2)*4]);
    // deferred diagonal phase: D(x) = B[j] * A[lane], x = 64j + lane
    {
      const float2 A = *(const float2*)&buf[LDS_APH + (L*64 + lane)*2];
      #pragma unroll
      for (int j = 0; j < 8; ++j){
        const float4 bq = *(const float4*)&buf[LDS_BPH + (L*8 + j)*4];
        const float2 P = make_float2(bq.x, bq.y);
        const float2 Q = make_float2(bq.z, bq.w);
        const float2 C  = pk_fma_lo(A, P, pk_mul_hi(A, Q));   // A*B[j]
        const float2 Dn = pk_swapneg(C, NEG1P1);              // (-Cy, Cx)
        amp[j] = pk_fma_lo(amp[j], C, pk_mul_hi(amp[j], Dn));
      }
    }
    // write with this layer's ring folded: x = 64j + lane -> phys(F(x))
    #pragma unroll
    for (int j = 0; j < 8; ++j) S[baseF ^ physmap(Fperm(j << 6))] = amp[j];
  }

  __syncthreads();                            // output reads other waves' arrays
  // transposed write of Re(state); state fully permuted -> linear element a.
  #pragma unroll
  for (int rep = 0; rep < 2; ++rep){
    const int a  = (tid >> 1) + rep*256;
    const int q  = tid & 1;
    const int pa = a ^ ((a >> 4) & 15);
    float4 vv;
    vv.x = st[q*4 + 0][pa].x;
    vv.y = st[q*4 + 1][pa].x;
    vv.z = st[q*4 + 2][pa].x;
    vv.w = st[q*4 + 3][pa].x;
    *(float4*)&out[(size_t)s*262144 + (size_t)a*512 + cb*8 + q*4] = vv;
  }
}

// ---------------- kernel 2: rank-2 expm correction on cols 0..71 ----------------
// out[:,0] = cos(th)*u0 - alpha*(U v)
// out[:,j] = U[:,j] + (alpha*u0 - beta*(U v)) * v[j]   (1<=j<72)
// One row per 4-lane quad; quad shuffle reduction; no LDS, no barriers.
__global__ __launch_bounds__(256)
void corr_kernel(const float* __restrict__ ws, float* __restrict__ out){
  const int s   = blockIdx.x >> 3;
  const int rg  = blockIdx.x & 7;
  const int qi  = threadIdx.x & 3;
  const int row = rg*64 + (threadIdx.x >> 2);
  const float* vp = ws + s*80;
  float* rowp = out + (size_t)s*262144 + (size_t)row*512;
  float2 x[9], vv[9];
  #pragma unroll
  for (int i = 0; i < 9; ++i){
    x[i]  = *(const float2*)(rowp + (qi*9 + i)*2);
    vv[i] = *(const float2*)(vp   + (qi*9 + i)*2);
  }
  float uv = 0.f;
  #pragma unroll
  for (int i = 0; i < 9; ++i)
    uv = fmaf(x[i].x, vv[i].x, fmaf(x[i].y, vv[i].y, uv));
  uv += __shfl_xor(uv, 1);
  uv += __shfl_xor(uv, 2);
  const float u0  = __shfl(x[0].x, 0, 4);     // quad lane 0's col-0 value
  const float cth = vp[72], alpha = vp[73], beta = vp[74];
  const float w  = fmaf(alpha, u0, -beta*uv);
  const float c0 = cth*u0 - alpha*uv;
  #pragma unroll
  for (int i = 0; i < 9; ++i){
    float2 o;
    o.x = fmaf(w, vv[i].x, x[i].x);
    o.y = fmaf(w, vv[i].y, x[i].y);
    if (qi == 0 && i == 0) o.x = c0;          // v[0]=0 left x unchanged; replace
    *(float2*)(rowp + (qi*9 + i)*2) = o;
  }
}

extern "C" void kernel_launch(void* const* d_in, const int* in_sizes, int n_in,
                              void* d_out, int out_size, void* d_ws, size_t ws_size,
                              hipStream_t stream){
  const float* t  = (const float*)d_in[0];
  const float* w1 = (const float*)d_in[1];
  const float* b1 = (const float*)d_in[2];
  const float* w2 = (const float*)d_in[3];
  const float* b2 = (const float*)d_in[4];
  float* out = (float*)d_out;
  float* ws  = (float*)d_ws;                  // 64*80 floats = 20 KiB used
  sim_kernel <<<4096, 512, 0, stream>>>(t, w1, b1, w2, b2, out, ws);
  corr_kernel<<<512,  256, 0, stream>>>(ws, out);
}